// Round 7
// baseline (244.006 us; speedup 1.0000x reference)
//
#include <hip/hip_runtime.h>
#include <hip/hip_bf16.h>

#define B_ 2
#define S_ 2048
#define H_ 2048
#define NH_ 16
#define NG_ 4
#define HD_ 128
#define HPG_ 4

typedef __attribute__((ext_vector_type(8))) short short8;
typedef __attribute__((ext_vector_type(4))) short short4v;
typedef __attribute__((ext_vector_type(4))) float float4v;

#define MFMA_BF16 __builtin_amdgcn_mfma_f32_16x16x32_bf16

#if __has_builtin(__builtin_amdgcn_exp2f)
#define EXP2(x) __builtin_amdgcn_exp2f(x)
#else
#define EXP2(x) exp2f(x)
#endif

// async global->LDS, 16B per lane. Per-lane lds ptr must equal wavebase + lane*16.
__device__ __forceinline__ void gload16(const void* g, void* l) {
    __builtin_amdgcn_global_load_lds(
        (const __attribute__((address_space(1))) unsigned int*)g,
        (__attribute__((address_space(3))) unsigned int*)l, 16, 0, 0);
}

__device__ __forceinline__ short bf16bits(float f) {
    union { __hip_bfloat16 h; short s; } u;
    u.h = __float2bfloat16(f);
    return u.s;
}

// ---------------- fused fp32 -> bf16 conversion + mask + bias concat ----------------
// chunk counts: hs 1048576, Wq 524288, Wk 131072, Wv 131072 -> total 1835008 = 7168*256
__global__ __launch_bounds__(256) void cvt_all(const float* __restrict__ hs,
                                               const float* __restrict__ wq,
                                               const float* __restrict__ wk,
                                               const float* __restrict__ wv,
                                               const int* __restrict__ mask,
                                               const float* __restrict__ bq,
                                               const float* __restrict__ bk,
                                               const float* __restrict__ bv,
                                               __hip_bfloat16* __restrict__ o_hs,
                                               __hip_bfloat16* __restrict__ o_wq,
                                               __hip_bfloat16* __restrict__ o_wk,
                                               __hip_bfloat16* __restrict__ o_wv,
                                               float* __restrict__ o_m,
                                               float* __restrict__ o_bc) {
    int i = blockIdx.x * 256 + threadIdx.x;
    if (blockIdx.x == 0) {
        // mask -> additive term (0 keep, -3e38 drop); exp2(-3e38) == 0
#pragma unroll
        for (int j = 0; j < 16; ++j) {
            int idx = threadIdx.x * 16 + j;
            o_m[idx] = mask[idx] ? 0.0f : -3.0e38f;
        }
    }
    if (blockIdx.x == 1) {
        // concatenated bias [3072] = bq | bk | bv
#pragma unroll
        for (int j = 0; j < 12; ++j) {
            int idx = j * 256 + threadIdx.x;
            float v = (idx < 2048) ? bq[idx] : (idx < 2560) ? bk[idx - 2048] : bv[idx - 2560];
            o_bc[idx] = v;
        }
    }
    const float* src;
    __hip_bfloat16* dst;
    int off;
    if (i < 1048576)      { src = hs; dst = o_hs; off = i; }
    else if (i < 1572864) { src = wq; dst = o_wq; off = i - 1048576; }
    else if (i < 1703936) { src = wk; dst = o_wk; off = i - 1572864; }
    else                  { src = wv; dst = o_wv; off = i - 1703936; }
    const float4* s4 = (const float4*)src;
    float4 a = s4[2 * (size_t)off];
    float4 b = s4[2 * (size_t)off + 1];
    union { short8 s; __hip_bfloat16 h[8]; } u;
    u.h[0] = __float2bfloat16(a.x); u.h[1] = __float2bfloat16(a.y);
    u.h[2] = __float2bfloat16(a.z); u.h[3] = __float2bfloat16(a.w);
    u.h[4] = __float2bfloat16(b.x); u.h[5] = __float2bfloat16(b.y);
    u.h[6] = __float2bfloat16(b.z); u.h[7] = __float2bfloat16(b.w);
    *(short8*)(dst + 8 * (size_t)off) = u.s;
}

// ---------------- fused q/k/v GEMM, 256x192 tile, 4-buffer counted-vmcnt pipeline ----------------
// (unchanged from round 2 -- verified)
__global__ __launch_bounds__(512, 2) void gemm_qkv3(const __hip_bfloat16* __restrict__ A,
                                                    const __hip_bfloat16* __restrict__ Wcat,
                                                    const float* __restrict__ biasC,
                                                    __hip_bfloat16* __restrict__ qO,
                                                    __hip_bfloat16* __restrict__ kO,
                                                    __hip_bfloat16* __restrict__ vTO) {
    extern __shared__ char lds[];  // 114688 B = 4 x 28672

    const int tid = threadIdx.x;
    const int lane = tid & 63;
    const int x = lane & 15, g = lane >> 4;
    const int wid = tid >> 6;            // 0..7
    const int wm = wid >> 2, wn = wid & 3;

    const int id0 = blockIdx.x;
    const int id = ((id0 & 7) << 5) | (id0 >> 3);
    const int bn_t = id >> 4, bm_t = id & 15;
    const int bm = bm_t * 256, bn = bn_t * 192;
    const int K = 2048;

    const int srow = tid >> 2;                         // 0..127
    const int schunk = (tid & 3) ^ ((tid >> 3) & 3);
    const __hip_bfloat16* gA0 = A + (size_t)(bm + srow) * K + schunk * 8;
    const __hip_bfloat16* gA1 = A + (size_t)(bm + 128 + srow) * K + schunk * 8;
    const __hip_bfloat16* gB0 = Wcat + (size_t)(bn + srow) * K + schunk * 8;
    const __hip_bfloat16* gB1 = Wcat + (size_t)(bn + 128 + srow) * K + schunk * 8;  // rows 128..191
    const bool doB1 = (tid < 256);

    const int xk = (x >> 1) & 3;
    int aoffA[8], boffB[3];
#pragma unroll
    for (int mb = 0; mb < 8; ++mb)
        aoffA[mb] = (wm * 128 + mb * 16 + x) * 64 + ((g ^ xk) * 16);
#pragma unroll
    for (int nb = 0; nb < 3; ++nb)
        boffB[nb] = 16384 + (wn * 48 + nb * 16 + x) * 64 + ((g ^ xk) * 16);

    float4v acc[8][3];
#pragma unroll
    for (int i = 0; i < 8; ++i)
#pragma unroll
        for (int j = 0; j < 3; ++j) acc[i][j] = (float4v)0.f;

    // prologue: stage K-tiles 0 -> buf0, 1 -> buf1
#pragma unroll
    for (int p = 0; p < 2; ++p) {
        char* stg = lds + p * 28672;
        gload16(gA0, stg + tid * 16);
        gload16(gA1, stg + 8192 + tid * 16);
        gload16(gB0, stg + 16384 + tid * 16);
        if (doB1) gload16(gB1, stg + 24576 + tid * 16);
        gA0 += 32; gA1 += 32; gB0 += 32; gB1 += 32;
    }
    if (doB1) asm volatile("s_waitcnt vmcnt(4)" ::: "memory");
    else      asm volatile("s_waitcnt vmcnt(3)" ::: "memory");
    __builtin_amdgcn_s_barrier();

#pragma unroll 4
    for (int t = 0; t < 64; ++t) {
        const char* bc = lds + (t & 3) * 28672;
        char* stg = lds + ((t + 2) & 3) * 28672;

        // ---- phase A: frags af[0..3] + all B frags; stage A of tile t+2 ----
        short8 afA[4], bfr[3];
#pragma unroll
        for (int mb = 0; mb < 4; ++mb) afA[mb] = *(const short8*)(bc + aoffA[mb]);
#pragma unroll
        for (int nb = 0; nb < 3; ++nb) bfr[nb] = *(const short8*)(bc + boffB[nb]);
        if (t < 62) {
            gload16(gA0, stg + tid * 16);
            gload16(gA1, stg + 8192 + tid * 16);
            gA0 += 32; gA1 += 32;
        }
        __builtin_amdgcn_s_barrier();
        asm volatile("s_waitcnt lgkmcnt(0)");
        __builtin_amdgcn_sched_barrier(0);
        __builtin_amdgcn_s_setprio(1);
#pragma unroll
        for (int mb = 0; mb < 4; ++mb)
#pragma unroll
            for (int nb = 0; nb < 3; ++nb)
                acc[mb][nb] = MFMA_BF16(afA[mb], bfr[nb], acc[mb][nb], 0, 0, 0);
        __builtin_amdgcn_s_setprio(0);
        __builtin_amdgcn_s_barrier();

        // ---- phase B: frags af[4..7] (B frags held in regs); stage B of tile t+2 ----
        short8 afB[4];
#pragma unroll
        for (int mb = 0; mb < 4; ++mb) afB[mb] = *(const short8*)(bc + aoffA[4 + mb]);
        if (t < 62) {
            gload16(gB0, stg + 16384 + tid * 16);
            if (doB1) gload16(gB1, stg + 24576 + tid * 16);
            gB0 += 32; gB1 += 32;
        }
        __builtin_amdgcn_s_barrier();
        asm volatile("s_waitcnt lgkmcnt(0)");
        __builtin_amdgcn_sched_barrier(0);
        __builtin_amdgcn_s_setprio(1);
#pragma unroll
        for (int mb = 0; mb < 4; ++mb)
#pragma unroll
            for (int nb = 0; nb < 3; ++nb)
                acc[4 + mb][nb] = MFMA_BF16(afB[mb], bfr[nb], acc[4 + mb][nb], 0, 0, 0);
        __builtin_amdgcn_s_setprio(0);
        if (t < 62) {
            if (doB1) asm volatile("s_waitcnt vmcnt(4)" ::: "memory");
            else      asm volatile("s_waitcnt vmcnt(3)" ::: "memory");
        } else {
            asm volatile("s_waitcnt vmcnt(0)" ::: "memory");
        }
        __builtin_amdgcn_s_barrier();
    }

    // epilogue: per-frag routing Q / K / V^T (16-col frags never straddle 2048/2560)
#pragma unroll
    for (int mb = 0; mb < 8; ++mb) {
#pragma unroll
        for (int nb = 0; nb < 3; ++nb) {
            const int n = bn + wn * 48 + nb * 16 + x;
            const float bsv = biasC[n];
            const int m0 = bm + wm * 128 + mb * 16 + g * 4;
            if (n < 2048) {
#pragma unroll
                for (int r = 0; r < 4; ++r)
                    qO[(size_t)(m0 + r) * 2048 + n] = __float2bfloat16(acc[mb][nb][r] + bsv);
            } else if (n < 2560) {
                const int nk = n - 2048;
#pragma unroll
                for (int r = 0; r < 4; ++r)
                    kO[(size_t)(m0 + r) * 512 + nk] = __float2bfloat16(acc[mb][nb][r] + bsv);
            } else {
                const int nv = n - 2560;
                const int gv = nv >> 7, d = nv & 127;
                const int bb2 = m0 >> 11, s = m0 & 2047;
                short4v pk;
#pragma unroll
                for (int r = 0; r < 4; ++r) pk[r] = bf16bits(acc[mb][nb][r] + bsv);
                *(short4v*)(vTO + ((size_t)(bb2 * NG_ + gv) * HD_ + d) * S_ + s) = pk;
            }
        }
    }
}

// ---------------- Flash attention, QBLK=256, PV pipelined one iter behind ----------------
// r6 post-mortem: MfmaUtil pinned ~34% across all occupancy/staging configs -> serial
// {QK -> softmax -> barrier -> PV -> barrier} chain is the cost. New schedule (1 barrier/iter):
//   barrier -> issue V(it) -> QK(it) -> PV(it-1) -> softmax(it) -> issue K(it+1)
// QK+PV form one 64-MFMA cluster; softmax's sc dependency hides behind PV's MFMA burst.
// All buffers double-buffered by parity (Ks2/Vs2/Ps2, LDS 135168 B, 1 block/CU -- grid=256
// forces 1/CU anyway). Race audit: every cross-wave edge (P->PV, V/K stage->consume) is
// separated by exactly one __syncthreads (implicit vmcnt(0) drains gload_lds); every buffer
// rewrite is barrier-separated from its last read via parity distance 2.
// T1: XCD swizzle, 32 blocks/XCD = exactly one (b,gi) KV slice (1MB, L2-resident).
__global__ __launch_bounds__(512, 2) void attn(const __hip_bfloat16* __restrict__ q,
                                               const __hip_bfloat16* __restrict__ k,
                                               const __hip_bfloat16* __restrict__ vT,
                                               const float* __restrict__ M,
                                               float* __restrict__ out) {
    extern __shared__ char smem[];  // 135168
    char* Ks = smem;                // 2 x 16384   [t=64][d=128] chunk-xor
    char* Vs = smem + 32768;        // 2 x 16384   [d=128][t=64] chunk-xor
    char* Ps = smem + 65536;        // 2 x 34816   [q=256] rows of 136B (0-conflict)

    const int tid = threadIdx.x;
    const int lane = tid & 63;
    const int w = tid >> 6;          // 0..7
    const int wm = w >> 2, wn = w & 3;
    const int x = lane & 15, g = lane >> 4;

    // XCD-aware swizzle: 256 blocks = 8 XCDs x 32; XCD xcd = (b<<2)|gi owns its KV slice.
    const int bid0 = blockIdx.x;
    const int bid = ((bid0 & 7) << 5) | (bid0 >> 3);
    const int qt = bid & 7;
    const int hp = (bid >> 3) & 3;
    const int gi = (bid >> 5) & 3;
    const int b = bid >> 7;
    const int head = gi * HPG_ + hp;
    const int q0 = qt * 256;

    // Q B-frags in registers: B[k=d][n=q]: n = wn*64+nb*16+x, k = ks*32+g*8+j
    short8 qf[4][4];
#pragma unroll
    for (int nb = 0; nb < 4; ++nb) {
        const int qq = q0 + wn * 64 + nb * 16 + x;
        const __hip_bfloat16* qrow = q + ((size_t)(b * S_ + qq) * NH_ + head) * HD_ + g * 8;
#pragma unroll
        for (int ks = 0; ks < 4; ++ks)
            qf[nb][ks] = *(const short8*)(qrow + ks * 32);
    }

    // K staging (512 thr, 2 rounds): dest row (tid>>4)+{0,32}, chunk tid&15; src chunk ^(row&15)
    const int kchunk = (tid & 15) ^ ((tid >> 4) & 15);
    const __hip_bfloat16* kp = k + ((size_t)(b * S_ + (tid >> 4)) * NG_ + gi) * HD_ + kchunk * 8;
    // V staging (2 rounds): dest d-row (tid>>3)+{0,64}, chunk tid&7; src chunk ^(row&7)
    const int vchunk = (tid & 7) ^ ((tid >> 3) & 7);
    const __hip_bfloat16* vp = vT + ((size_t)(b * NG_ + gi) * HD_ + (tid >> 3)) * S_ + vchunk * 8;
    const float* mp = M + b * S_ + wm * 32 + g * 4;

    float4v O[4][4];
#pragma unroll
    for (int i = 0; i < 4; ++i)
#pragma unroll
        for (int j = 0; j < 4; ++j) O[i][j] = (float4v)0.f;
    float l_part[4] = {0.f, 0.f, 0.f, 0.f};
    float4v sc[2][4];

    const float SM = 0.08838834764831845f * 1.4426950408889634f;  // scale * log2(e)

    auto QKf = [&](const char* KsC) {
#pragma unroll
        for (int i = 0; i < 2; ++i)
#pragma unroll
            for (int j = 0; j < 4; ++j) sc[i][j] = (float4v)0.f;
        __builtin_amdgcn_s_setprio(1);
#pragma unroll
        for (int ks = 0; ks < 4; ++ks) {
            short8 af0 = *(const short8*)(KsC + (wm * 32 + x) * 256 + (((ks * 4 + g) ^ x) * 16));
            short8 af1 = *(const short8*)(KsC + (wm * 32 + 16 + x) * 256 + (((ks * 4 + g) ^ x) * 16));
#pragma unroll
            for (int nb = 0; nb < 4; ++nb) {
                sc[0][nb] = MFMA_BF16(af0, qf[nb][ks], sc[0][nb], 0, 0, 0);
                sc[1][nb] = MFMA_BF16(af1, qf[nb][ks], sc[1][nb], 0, 0, 0);
            }
        }
        __builtin_amdgcn_s_setprio(0);
    };

    auto PVf = [&](const char* VsP, const char* PsP) {
#pragma unroll
        for (int ks = 0; ks < 2; ++ks) {
            short8 vf[4], pf[4];
#pragma unroll
            for (int i4 = 0; i4 < 4; ++i4) {
                vf[i4] = *(const short8*)(VsP + (wm * 64 + i4 * 16 + x) * 128 +
                                          (((ks * 4 + g) ^ (x & 7)) * 16));
                const char* pb = PsP + (wn * 64 + i4 * 16 + x) * 136 + (8 * ks + 2 * g) * 8;
                union { short4v h[2]; short8 s8; } uu;
                uu.h[0] = *(const short4v*)pb;
                uu.h[1] = *(const short4v*)(pb + 8);
                pf[i4] = uu.s8;
            }
            __builtin_amdgcn_s_setprio(1);
#pragma unroll
            for (int mb = 0; mb < 4; ++mb)
#pragma unroll
                for (int nb = 0; nb < 4; ++nb)
                    O[mb][nb] = MFMA_BF16(vf[mb], pf[nb], O[mb][nb], 0, 0, 0);
            __builtin_amdgcn_s_setprio(0);
        }
    };

    auto SMf = [&](char* PsC, float4 mv0, float4 mv1) {
#pragma unroll
        for (int mb = 0; mb < 2; ++mb) {
            const float4 mv = mb ? mv1 : mv0;
            const int hs = wm * 8 + mb * 4 + g;  // t-halfslot 0..15
#pragma unroll
            for (int nb = 0; nb < 4; ++nb) {
                float p0 = EXP2(fmaf(sc[mb][nb][0], SM, mv.x));
                float p1 = EXP2(fmaf(sc[mb][nb][1], SM, mv.y));
                float p2 = EXP2(fmaf(sc[mb][nb][2], SM, mv.z));
                float p3 = EXP2(fmaf(sc[mb][nb][3], SM, mv.w));
                l_part[nb] += (p0 + p1) + (p2 + p3);
                short4v pk;
                pk[0] = bf16bits(p0); pk[1] = bf16bits(p1);
                pk[2] = bf16bits(p2); pk[3] = bf16bits(p3);
                *(short4v*)(PsC + (wn * 64 + nb * 16 + x) * 136 + hs * 8) = pk;
            }
        }
    };

    // prologue: K(0) -> Ks[0]
    gload16(kp, Ks + tid * 16);
    gload16(kp + 16384, Ks + tid * 16 + 8192);
    kp += 32768;
    __syncthreads();  // K(0) resident

    // it = 0 (no PV)
    {
        float4 mv0 = *(const float4*)(mp);
        float4 mv1 = *(const float4*)(mp + 16);
        mp += 64;
        gload16(vp, Vs + tid * 16);              // V(0) -> Vs[0]
        gload16(vp + 131072, Vs + tid * 16 + 8192);
        vp += 64;
        QKf(Ks);
        SMf(Ps, mv0, mv1);                       // P(0) -> Ps[0]
        gload16(kp, Ks + 16384 + tid * 16);      // K(1) -> Ks[1]
        gload16(kp + 16384, Ks + 16384 + tid * 16 + 8192);
        kp += 32768;
    }

#pragma unroll 2
    for (int it = 1; it < 32; ++it) {
        __syncthreads();  // K(it),V(it-1) resident; P(it-1) published; buffers of it-2 free
        const int p = it & 1;
        char* KsC = Ks + p * 16384;
        char* VsN = Vs + p * 16384;
        char* VsP = Vs + (p ^ 1) * 16384;
        char* PsC = Ps + p * 34816;
        char* PsP = Ps + (p ^ 1) * 34816;

        float4 mv0 = *(const float4*)(mp);
        float4 mv1 = *(const float4*)(mp + 16);
        mp += 64;
        gload16(vp, VsN + tid * 16);             // V(it)
        gload16(vp + 131072, VsN + tid * 16 + 8192);
        vp += 64;

        QKf(KsC);                                // QK(it): 32 MFMA
        PVf(VsP, PsP);                           // PV(it-1): 32 MFMA, same cluster
        SMf(PsC, mv0, mv1);                      // softmax(it)

        if (it < 31) {                           // K(it+1) -> Ks[p^1]
            char* KsN = Ks + (p ^ 1) * 16384;
            gload16(kp, KsN + tid * 16);
            gload16(kp + 16384, KsN + tid * 16 + 8192);
            kp += 32768;
        }
    }

    __syncthreads();                             // P(31),V(31) ready
    PVf(Vs + 16384, Ps + 34816);                 // PV(31), parity 1

    // final l reduction: over g (shuffles), then across wm pair (LDS)
#pragma unroll
    for (int nb = 0; nb < 4; ++nb) {
        l_part[nb] += __shfl_xor(l_part[nb], 16);
        l_part[nb] += __shfl_xor(l_part[nb], 32);
    }
    float* lws = (float*)Ps;  // Ps[0] region, disjoint from PV(31)'s Ps[1] reads
    if (g == 0) {
#pragma unroll
        for (int nb = 0; nb < 4; ++nb)
            lws[wm * 256 + wn * 64 + nb * 16 + x] = l_part[nb];
    }
    __syncthreads();
    float inv[4];
#pragma unroll
    for (int nb = 0; nb < 4; ++nb)
        inv[nb] = 1.0f / (l_part[nb] + lws[(wm ^ 1) * 256 + wn * 64 + nb * 16 + x]);

    // epilogue: out[b, q0+q, head*128 + d]; reg r -> consecutive d -> float4 stores
#pragma unroll
    for (int mb = 0; mb < 4; ++mb) {
#pragma unroll
        for (int nb = 0; nb < 4; ++nb) {
            const int qq = q0 + wn * 64 + nb * 16 + x;
            const int d0 = wm * 64 + mb * 16 + g * 4;
            float4v o = O[mb][nb] * inv[nb];
            *(float4v*)(out + (size_t)(b * S_ + qq) * H_ + head * HD_ + d0) = o;
        }
    }
}

extern "C" void kernel_launch(void* const* d_in, const int* in_sizes, int n_in,
                              void* d_out, int out_size, void* d_ws, size_t ws_size,
                              hipStream_t stream) {
    (void)in_sizes; (void)n_in; (void)out_size; (void)ws_size;
    const float* hs = (const float*)d_in[0];
    const int* amask = (const int*)d_in[1];
    const float* Wq = (const float*)d_in[2];
    const float* bq = (const float*)d_in[3];
    const float* Wk = (const float*)d_in[4];
    const float* bk = (const float*)d_in[5];
    const float* Wv = (const float*)d_in[6];
    const float* bv = (const float*)d_in[7];
    float* out = (float*)d_out;

    char* ws = (char*)d_ws;
    __hip_bfloat16* hsB = (__hip_bfloat16*)(ws);              // 16 MB
    __hip_bfloat16* WqB = (__hip_bfloat16*)(ws + 16777216);   // 8 MB  -- Wq|Wk|Wv contiguous = Wcat [3072][2048]
    __hip_bfloat16* WkB = (__hip_bfloat16*)(ws + 25165824);   // 2 MB
    __hip_bfloat16* WvB = (__hip_bfloat16*)(ws + 27262976);   // 2 MB
    __hip_bfloat16* qB  = (__hip_bfloat16*)(ws + 29360128);   // 16 MB  [B,S,NH,HD]
    __hip_bfloat16* kB  = (__hip_bfloat16*)(ws + 46137344);   // 4 MB   [B,S,NG,HD]
    __hip_bfloat16* vTB = (__hip_bfloat16*)(ws + 50331648);   // 4 MB   [B,NG,HD,S]
    float* Mf           = (float*)(ws + 54525952);            // 16 KB  mask additive term
    float* biasC        = (float*)(ws + 54542336);            // 12 KB  bias concat [3072]

    hipFuncSetAttribute((const void*)gemm_qkv3,
                        hipFuncAttributeMaxDynamicSharedMemorySize, 114688);
    hipFuncSetAttribute((const void*)attn,
                        hipFuncAttributeMaxDynamicSharedMemorySize, 135168);

    cvt_all<<<7168, 256, 0, stream>>>(hs, Wq, Wk, Wv, amask, bq, bk, bv,
                                      hsB, WqB, WkB, WvB, Mf, biasC);
    gemm_qkv3<<<256, 512, 114688, stream>>>(hsB, WqB, biasC, qB, kB, vTB);
    attn<<<256, 512, 135168, stream>>>(qB, kB, vTB, Mf, out);
}

// Round 8
// 234.661 us; speedup vs baseline: 1.0398x; 1.0398x over previous
//
#include <hip/hip_runtime.h>
#include <hip/hip_bf16.h>

#define B_ 2
#define S_ 2048
#define H_ 2048
#define NH_ 16
#define NG_ 4
#define HD_ 128
#define HPG_ 4

typedef __attribute__((ext_vector_type(8))) short short8;
typedef __attribute__((ext_vector_type(4))) short short4v;
typedef __attribute__((ext_vector_type(4))) float float4v;

#define MFMA_BF16 __builtin_amdgcn_mfma_f32_16x16x32_bf16

#if __has_builtin(__builtin_amdgcn_exp2f)
#define EXP2(x) __builtin_amdgcn_exp2f(x)
#else
#define EXP2(x) exp2f(x)
#endif

// async global->LDS, 16B per lane. Per-lane lds ptr must equal wavebase + lane*16.
__device__ __forceinline__ void gload16(const void* g, void* l) {
    __builtin_amdgcn_global_load_lds(
        (const __attribute__((address_space(1))) unsigned int*)g,
        (__attribute__((address_space(3))) unsigned int*)l, 16, 0, 0);
}

__device__ __forceinline__ short bf16bits(float f) {
    union { __hip_bfloat16 h; short s; } u;
    u.h = __float2bfloat16(f);
    return u.s;
}

// ---------------- fused fp32 -> bf16 conversion + mask + bias concat ----------------
// chunk counts: hs 1048576, Wq 524288, Wk 131072, Wv 131072 -> total 1835008 = 7168*256
__global__ __launch_bounds__(256) void cvt_all(const float* __restrict__ hs,
                                               const float* __restrict__ wq,
                                               const float* __restrict__ wk,
                                               const float* __restrict__ wv,
                                               const int* __restrict__ mask,
                                               const float* __restrict__ bq,
                                               const float* __restrict__ bk,
                                               const float* __restrict__ bv,
                                               __hip_bfloat16* __restrict__ o_hs,
                                               __hip_bfloat16* __restrict__ o_wq,
                                               __hip_bfloat16* __restrict__ o_wk,
                                               __hip_bfloat16* __restrict__ o_wv,
                                               float* __restrict__ o_m,
                                               float* __restrict__ o_bc) {
    int i = blockIdx.x * 256 + threadIdx.x;
    if (blockIdx.x == 0) {
        // mask -> additive term (0 keep, -3e38 drop); exp2(-3e38) == 0
#pragma unroll
        for (int j = 0; j < 16; ++j) {
            int idx = threadIdx.x * 16 + j;
            o_m[idx] = mask[idx] ? 0.0f : -3.0e38f;
        }
    }
    if (blockIdx.x == 1) {
        // concatenated bias [3072] = bq | bk | bv
#pragma unroll
        for (int j = 0; j < 12; ++j) {
            int idx = j * 256 + threadIdx.x;
            float v = (idx < 2048) ? bq[idx] : (idx < 2560) ? bk[idx - 2048] : bv[idx - 2560];
            o_bc[idx] = v;
        }
    }
    const float* src;
    __hip_bfloat16* dst;
    int off;
    if (i < 1048576)      { src = hs; dst = o_hs; off = i; }
    else if (i < 1572864) { src = wq; dst = o_wq; off = i - 1048576; }
    else if (i < 1703936) { src = wk; dst = o_wk; off = i - 1572864; }
    else                  { src = wv; dst = o_wv; off = i - 1703936; }
    const float4* s4 = (const float4*)src;
    float4 a = s4[2 * (size_t)off];
    float4 b = s4[2 * (size_t)off + 1];
    union { short8 s; __hip_bfloat16 h[8]; } u;
    u.h[0] = __float2bfloat16(a.x); u.h[1] = __float2bfloat16(a.y);
    u.h[2] = __float2bfloat16(a.z); u.h[3] = __float2bfloat16(a.w);
    u.h[4] = __float2bfloat16(b.x); u.h[5] = __float2bfloat16(b.y);
    u.h[6] = __float2bfloat16(b.z); u.h[7] = __float2bfloat16(b.w);
    *(short8*)(dst + 8 * (size_t)off) = u.s;
}

// ---------------- fused q/k/v GEMM, 256x192 tile, 4-buffer counted-vmcnt pipeline ----------------
// (unchanged from round 2 -- verified)
__global__ __launch_bounds__(512, 2) void gemm_qkv3(const __hip_bfloat16* __restrict__ A,
                                                    const __hip_bfloat16* __restrict__ Wcat,
                                                    const float* __restrict__ biasC,
                                                    __hip_bfloat16* __restrict__ qO,
                                                    __hip_bfloat16* __restrict__ kO,
                                                    __hip_bfloat16* __restrict__ vTO) {
    extern __shared__ char lds[];  // 114688 B = 4 x 28672

    const int tid = threadIdx.x;
    const int lane = tid & 63;
    const int x = lane & 15, g = lane >> 4;
    const int wid = tid >> 6;            // 0..7
    const int wm = wid >> 2, wn = wid & 3;

    const int id0 = blockIdx.x;
    const int id = ((id0 & 7) << 5) | (id0 >> 3);
    const int bn_t = id >> 4, bm_t = id & 15;
    const int bm = bm_t * 256, bn = bn_t * 192;
    const int K = 2048;

    const int srow = tid >> 2;                         // 0..127
    const int schunk = (tid & 3) ^ ((tid >> 3) & 3);
    const __hip_bfloat16* gA0 = A + (size_t)(bm + srow) * K + schunk * 8;
    const __hip_bfloat16* gA1 = A + (size_t)(bm + 128 + srow) * K + schunk * 8;
    const __hip_bfloat16* gB0 = Wcat + (size_t)(bn + srow) * K + schunk * 8;
    const __hip_bfloat16* gB1 = Wcat + (size_t)(bn + 128 + srow) * K + schunk * 8;  // rows 128..191
    const bool doB1 = (tid < 256);

    const int xk = (x >> 1) & 3;
    int aoffA[8], boffB[3];
#pragma unroll
    for (int mb = 0; mb < 8; ++mb)
        aoffA[mb] = (wm * 128 + mb * 16 + x) * 64 + ((g ^ xk) * 16);
#pragma unroll
    for (int nb = 0; nb < 3; ++nb)
        boffB[nb] = 16384 + (wn * 48 + nb * 16 + x) * 64 + ((g ^ xk) * 16);

    float4v acc[8][3];
#pragma unroll
    for (int i = 0; i < 8; ++i)
#pragma unroll
        for (int j = 0; j < 3; ++j) acc[i][j] = (float4v)0.f;

    // prologue: stage K-tiles 0 -> buf0, 1 -> buf1
#pragma unroll
    for (int p = 0; p < 2; ++p) {
        char* stg = lds + p * 28672;
        gload16(gA0, stg + tid * 16);
        gload16(gA1, stg + 8192 + tid * 16);
        gload16(gB0, stg + 16384 + tid * 16);
        if (doB1) gload16(gB1, stg + 24576 + tid * 16);
        gA0 += 32; gA1 += 32; gB0 += 32; gB1 += 32;
    }
    if (doB1) asm volatile("s_waitcnt vmcnt(4)" ::: "memory");
    else      asm volatile("s_waitcnt vmcnt(3)" ::: "memory");
    __builtin_amdgcn_s_barrier();

#pragma unroll 4
    for (int t = 0; t < 64; ++t) {
        const char* bc = lds + (t & 3) * 28672;
        char* stg = lds + ((t + 2) & 3) * 28672;

        // ---- phase A: frags af[0..3] + all B frags; stage A of tile t+2 ----
        short8 afA[4], bfr[3];
#pragma unroll
        for (int mb = 0; mb < 4; ++mb) afA[mb] = *(const short8*)(bc + aoffA[mb]);
#pragma unroll
        for (int nb = 0; nb < 3; ++nb) bfr[nb] = *(const short8*)(bc + boffB[nb]);
        if (t < 62) {
            gload16(gA0, stg + tid * 16);
            gload16(gA1, stg + 8192 + tid * 16);
            gA0 += 32; gA1 += 32;
        }
        __builtin_amdgcn_s_barrier();
        asm volatile("s_waitcnt lgkmcnt(0)");
        __builtin_amdgcn_sched_barrier(0);
        __builtin_amdgcn_s_setprio(1);
#pragma unroll
        for (int mb = 0; mb < 4; ++mb)
#pragma unroll
            for (int nb = 0; nb < 3; ++nb)
                acc[mb][nb] = MFMA_BF16(afA[mb], bfr[nb], acc[mb][nb], 0, 0, 0);
        __builtin_amdgcn_s_setprio(0);
        __builtin_amdgcn_s_barrier();

        // ---- phase B: frags af[4..7] (B frags held in regs); stage B of tile t+2 ----
        short8 afB[4];
#pragma unroll
        for (int mb = 0; mb < 4; ++mb) afB[mb] = *(const short8*)(bc + aoffA[4 + mb]);
        if (t < 62) {
            gload16(gB0, stg + 16384 + tid * 16);
            if (doB1) gload16(gB1, stg + 24576 + tid * 16);
            gB0 += 32; gB1 += 32;
        }
        __builtin_amdgcn_s_barrier();
        asm volatile("s_waitcnt lgkmcnt(0)");
        __builtin_amdgcn_sched_barrier(0);
        __builtin_amdgcn_s_setprio(1);
#pragma unroll
        for (int mb = 0; mb < 4; ++mb)
#pragma unroll
            for (int nb = 0; nb < 3; ++nb)
                acc[4 + mb][nb] = MFMA_BF16(afB[mb], bfr[nb], acc[4 + mb][nb], 0, 0, 0);
        __builtin_amdgcn_s_setprio(0);
        if (t < 62) {
            if (doB1) asm volatile("s_waitcnt vmcnt(4)" ::: "memory");
            else      asm volatile("s_waitcnt vmcnt(3)" ::: "memory");
        } else {
            asm volatile("s_waitcnt vmcnt(0)" ::: "memory");
        }
        __builtin_amdgcn_s_barrier();
    }

    // epilogue: per-frag routing Q / K / V^T (16-col frags never straddle 2048/2560)
#pragma unroll
    for (int mb = 0; mb < 8; ++mb) {
#pragma unroll
        for (int nb = 0; nb < 3; ++nb) {
            const int n = bn + wn * 48 + nb * 16 + x;
            const float bsv = biasC[n];
            const int m0 = bm + wm * 128 + mb * 16 + g * 4;
            if (n < 2048) {
#pragma unroll
                for (int r = 0; r < 4; ++r)
                    qO[(size_t)(m0 + r) * 2048 + n] = __float2bfloat16(acc[mb][nb][r] + bsv);
            } else if (n < 2560) {
                const int nk = n - 2048;
#pragma unroll
                for (int r = 0; r < 4; ++r)
                    kO[(size_t)(m0 + r) * 512 + nk] = __float2bfloat16(acc[mb][nb][r] + bsv);
            } else {
                const int nv = n - 2560;
                const int gv = nv >> 7, d = nv & 127;
                const int bb2 = m0 >> 11, s = m0 & 2047;
                short4v pk;
#pragma unroll
                for (int r = 0; r < 4; ++r) pk[r] = bf16bits(acc[mb][nb][r] + bsv);
                *(short4v*)(vTO + ((size_t)(bb2 * NG_ + gv) * HD_ + d) * S_ + s) = pk;
            }
        }
    }
}

// ---------------- Flash attention, QBLK=256, PV pipelined, early load-issue ----------------
// r7 post-mortem: 1-barrier schedule regressed because (a) K(it+1) was issued immediately
// before the barrier's vmcnt(0) drain (zero latency cover) and (b) sc[2][4] stayed live
// across PV (+24 VGPR, spill traffic: WRITE +7.5MB). Fix, keeping 1 barrier/iter:
//   barrier -> issue V(it) AND K(it+1) -> QK(it) -> softmax(it) -> PV(it-1)
// Both loads get the full compute phase (~3000 cyc) before the next drain; sc dies at
// softmax so PV runs at low pressure. SM and PV are register-independent (scheduler
// interleaves VALU with PV's MFMA/ds_reads).
// Race audit (parity dbuf, distance 2): Ks[p^1] write vs QK(it-1) read -- barrier-sep;
// Vs[p] write vs PV(it-2) read (ran in iter it-1) -- barrier-sep; Ps[p] SM-write vs
// PV(it-2) read -- barrier-sep; PV(it-1) reads [p^1] buffers, disjoint from [p] writes.
// T1: XCD swizzle, 32 blocks/XCD = exactly one (b,gi) KV slice (1MB, L2-resident).
__global__ __launch_bounds__(512, 2) void attn(const __hip_bfloat16* __restrict__ q,
                                               const __hip_bfloat16* __restrict__ k,
                                               const __hip_bfloat16* __restrict__ vT,
                                               const float* __restrict__ M,
                                               float* __restrict__ out) {
    extern __shared__ char smem[];  // 135168
    char* Ks = smem;                // 2 x 16384   [t=64][d=128] chunk-xor
    char* Vs = smem + 32768;        // 2 x 16384   [d=128][t=64] chunk-xor
    char* Ps = smem + 65536;        // 2 x 34816   [q=256] rows of 136B (0-conflict)

    const int tid = threadIdx.x;
    const int lane = tid & 63;
    const int w = tid >> 6;          // 0..7
    const int wm = w >> 2, wn = w & 3;
    const int x = lane & 15, g = lane >> 4;

    // XCD-aware swizzle: 256 blocks = 8 XCDs x 32; XCD xcd = (b<<2)|gi owns its KV slice.
    const int bid0 = blockIdx.x;
    const int bid = ((bid0 & 7) << 5) | (bid0 >> 3);
    const int qt = bid & 7;
    const int hp = (bid >> 3) & 3;
    const int gi = (bid >> 5) & 3;
    const int b = bid >> 7;
    const int head = gi * HPG_ + hp;
    const int q0 = qt * 256;

    // Q B-frags in registers: B[k=d][n=q]: n = wn*64+nb*16+x, k = ks*32+g*8+j
    short8 qf[4][4];
#pragma unroll
    for (int nb = 0; nb < 4; ++nb) {
        const int qq = q0 + wn * 64 + nb * 16 + x;
        const __hip_bfloat16* qrow = q + ((size_t)(b * S_ + qq) * NH_ + head) * HD_ + g * 8;
#pragma unroll
        for (int ks = 0; ks < 4; ++ks)
            qf[nb][ks] = *(const short8*)(qrow + ks * 32);
    }

    // K staging (512 thr, 2 rounds): dest row (tid>>4)+{0,32}, chunk tid&15; src chunk ^(row&15)
    const int kchunk = (tid & 15) ^ ((tid >> 4) & 15);
    const __hip_bfloat16* kp = k + ((size_t)(b * S_ + (tid >> 4)) * NG_ + gi) * HD_ + kchunk * 8;
    // V staging (2 rounds): dest d-row (tid>>3)+{0,64}, chunk tid&7; src chunk ^(row&7)
    const int vchunk = (tid & 7) ^ ((tid >> 3) & 7);
    const __hip_bfloat16* vp = vT + ((size_t)(b * NG_ + gi) * HD_ + (tid >> 3)) * S_ + vchunk * 8;
    const float* mp = M + b * S_ + wm * 32 + g * 4;

    float4v O[4][4];
#pragma unroll
    for (int i = 0; i < 4; ++i)
#pragma unroll
        for (int j = 0; j < 4; ++j) O[i][j] = (float4v)0.f;
    float l_part[4] = {0.f, 0.f, 0.f, 0.f};
    float4v sc[2][4];

    const float SM = 0.08838834764831845f * 1.4426950408889634f;  // scale * log2(e)

    auto QKf = [&](const char* KsC) {
#pragma unroll
        for (int i = 0; i < 2; ++i)
#pragma unroll
            for (int j = 0; j < 4; ++j) sc[i][j] = (float4v)0.f;
        __builtin_amdgcn_s_setprio(1);
#pragma unroll
        for (int ks = 0; ks < 4; ++ks) {
            short8 af0 = *(const short8*)(KsC + (wm * 32 + x) * 256 + (((ks * 4 + g) ^ x) * 16));
            short8 af1 = *(const short8*)(KsC + (wm * 32 + 16 + x) * 256 + (((ks * 4 + g) ^ x) * 16));
#pragma unroll
            for (int nb = 0; nb < 4; ++nb) {
                sc[0][nb] = MFMA_BF16(af0, qf[nb][ks], sc[0][nb], 0, 0, 0);
                sc[1][nb] = MFMA_BF16(af1, qf[nb][ks], sc[1][nb], 0, 0, 0);
            }
        }
        __builtin_amdgcn_s_setprio(0);
    };

    auto PVf = [&](const char* VsP, const char* PsP) {
#pragma unroll
        for (int ks = 0; ks < 2; ++ks) {
            short8 vf[4], pf[4];
#pragma unroll
            for (int i4 = 0; i4 < 4; ++i4) {
                vf[i4] = *(const short8*)(VsP + (wm * 64 + i4 * 16 + x) * 128 +
                                          (((ks * 4 + g) ^ (x & 7)) * 16));
                const char* pb = PsP + (wn * 64 + i4 * 16 + x) * 136 + (8 * ks + 2 * g) * 8;
                union { short4v h[2]; short8 s8; } uu;
                uu.h[0] = *(const short4v*)pb;
                uu.h[1] = *(const short4v*)(pb + 8);
                pf[i4] = uu.s8;
            }
            __builtin_amdgcn_s_setprio(1);
#pragma unroll
            for (int mb = 0; mb < 4; ++mb)
#pragma unroll
                for (int nb = 0; nb < 4; ++nb)
                    O[mb][nb] = MFMA_BF16(vf[mb], pf[nb], O[mb][nb], 0, 0, 0);
            __builtin_amdgcn_s_setprio(0);
        }
    };

    auto SMf = [&](char* PsC, float4 mv0, float4 mv1) {
#pragma unroll
        for (int mb = 0; mb < 2; ++mb) {
            const float4 mv = mb ? mv1 : mv0;
            const int hs = wm * 8 + mb * 4 + g;  // t-halfslot 0..15
#pragma unroll
            for (int nb = 0; nb < 4; ++nb) {
                float p0 = EXP2(fmaf(sc[mb][nb][0], SM, mv.x));
                float p1 = EXP2(fmaf(sc[mb][nb][1], SM, mv.y));
                float p2 = EXP2(fmaf(sc[mb][nb][2], SM, mv.z));
                float p3 = EXP2(fmaf(sc[mb][nb][3], SM, mv.w));
                l_part[nb] += (p0 + p1) + (p2 + p3);
                short4v pk;
                pk[0] = bf16bits(p0); pk[1] = bf16bits(p1);
                pk[2] = bf16bits(p2); pk[3] = bf16bits(p3);
                *(short4v*)(PsC + (wn * 64 + nb * 16 + x) * 136 + hs * 8) = pk;
            }
        }
    };

    // prologue: K(0) -> Ks[0]
    gload16(kp, Ks + tid * 16);
    gload16(kp + 16384, Ks + tid * 16 + 8192);
    kp += 32768;
    __syncthreads();  // K(0) resident

    // it = 0 (no PV): issue V(0) and K(1) up front, both covered by QK0+SM0
    {
        float4 mv0 = *(const float4*)(mp);
        float4 mv1 = *(const float4*)(mp + 16);
        mp += 64;
        gload16(vp, Vs + tid * 16);              // V(0) -> Vs[0]
        gload16(vp + 131072, Vs + tid * 16 + 8192);
        vp += 64;
        gload16(kp, Ks + 16384 + tid * 16);      // K(1) -> Ks[1]
        gload16(kp + 16384, Ks + 16384 + tid * 16 + 8192);
        kp += 32768;
        QKf(Ks);
        SMf(Ps, mv0, mv1);                       // P(0) -> Ps[0]
    }

#pragma unroll 2
    for (int it = 1; it < 32; ++it) {
        __syncthreads();  // K(it),V(it-1) resident; P(it-1) published; buffers of it-2 free
        const int p = it & 1;
        char* KsC = Ks + p * 16384;
        char* VsN = Vs + p * 16384;
        char* VsP = Vs + (p ^ 1) * 16384;
        char* PsC = Ps + p * 34816;
        char* PsP = Ps + (p ^ 1) * 34816;

        float4 mv0 = *(const float4*)(mp);
        float4 mv1 = *(const float4*)(mp + 16);
        mp += 64;
        gload16(vp, VsN + tid * 16);             // V(it) -> Vs[p]
        gload16(vp + 131072, VsN + tid * 16 + 8192);
        vp += 64;
        if (it < 31) {                           // K(it+1) -> Ks[p^1]; last read QK(it-1) pre-barrier
            char* KsN = Ks + (p ^ 1) * 16384;
            gload16(kp, KsN + tid * 16);
            gload16(kp + 16384, KsN + tid * 16 + 8192);
            kp += 32768;
        }

        QKf(KsC);                                // QK(it): 32 MFMA
        SMf(PsC, mv0, mv1);                      // softmax(it): sc dies here
        PVf(VsP, PsP);                           // PV(it-1): 32 MFMA, low pressure
    }

    __syncthreads();                             // P(31),V(31) ready
    PVf(Vs + 16384, Ps + 34816);                 // PV(31), parity 1

    // final l reduction: over g (shuffles), then across wm pair (LDS)
#pragma unroll
    for (int nb = 0; nb < 4; ++nb) {
        l_part[nb] += __shfl_xor(l_part[nb], 16);
        l_part[nb] += __shfl_xor(l_part[nb], 32);
    }
    float* lws = (float*)Ps;  // Ps[0] region, disjoint from PV(31)'s Ps[1] reads
    if (g == 0) {
#pragma unroll
        for (int nb = 0; nb < 4; ++nb)
            lws[wm * 256 + wn * 64 + nb * 16 + x] = l_part[nb];
    }
    __syncthreads();
    float inv[4];
#pragma unroll
    for (int nb = 0; nb < 4; ++nb)
        inv[nb] = 1.0f / (l_part[nb] + lws[(wm ^ 1) * 256 + wn * 64 + nb * 16 + x]);

    // epilogue: out[b, q0+q, head*128 + d]; reg r -> consecutive d -> float4 stores
#pragma unroll
    for (int mb = 0; mb < 4; ++mb) {
#pragma unroll
        for (int nb = 0; nb < 4; ++nb) {
            const int qq = q0 + wn * 64 + nb * 16 + x;
            const int d0 = wm * 64 + mb * 16 + g * 4;
            float4v o = O[mb][nb] * inv[nb];
            *(float4v*)(out + (size_t)(b * S_ + qq) * H_ + head * HD_ + d0) = o;
        }
    }
}

extern "C" void kernel_launch(void* const* d_in, const int* in_sizes, int n_in,
                              void* d_out, int out_size, void* d_ws, size_t ws_size,
                              hipStream_t stream) {
    (void)in_sizes; (void)n_in; (void)out_size; (void)ws_size;
    const float* hs = (const float*)d_in[0];
    const int* amask = (const int*)d_in[1];
    const float* Wq = (const float*)d_in[2];
    const float* bq = (const float*)d_in[3];
    const float* Wk = (const float*)d_in[4];
    const float* bk = (const float*)d_in[5];
    const float* Wv = (const float*)d_in[6];
    const float* bv = (const float*)d_in[7];
    float* out = (float*)d_out;

    char* ws = (char*)d_ws;
    __hip_bfloat16* hsB = (__hip_bfloat16*)(ws);              // 16 MB
    __hip_bfloat16* WqB = (__hip_bfloat16*)(ws + 16777216);   // 8 MB  -- Wq|Wk|Wv contiguous = Wcat [3072][2048]
    __hip_bfloat16* WkB = (__hip_bfloat16*)(ws + 25165824);   // 2 MB
    __hip_bfloat16* WvB = (__hip_bfloat16*)(ws + 27262976);   // 2 MB
    __hip_bfloat16* qB  = (__hip_bfloat16*)(ws + 29360128);   // 16 MB  [B,S,NH,HD]
    __hip_bfloat16* kB  = (__hip_bfloat16*)(ws + 46137344);   // 4 MB   [B,S,NG,HD]
    __hip_bfloat16* vTB = (__hip_bfloat16*)(ws + 50331648);   // 4 MB   [B,NG,HD,S]
    float* Mf           = (float*)(ws + 54525952);            // 16 KB  mask additive term
    float* biasC        = (float*)(ws + 54542336);            // 12 KB  bias concat [3072]

    hipFuncSetAttribute((const void*)gemm_qkv3,
                        hipFuncAttributeMaxDynamicSharedMemorySize, 114688);
    hipFuncSetAttribute((const void*)attn,
                        hipFuncAttributeMaxDynamicSharedMemorySize, 135168);

    cvt_all<<<7168, 256, 0, stream>>>(hs, Wq, Wk, Wv, amask, bq, bk, bv,
                                      hsB, WqB, WkB, WvB, Mf, biasC);
    gemm_qkv3<<<256, 512, 114688, stream>>>(hsB, WqB, biasC, qB, kB, vTB);
    attn<<<256, 512, 135168, stream>>>(qB, kB, vTB, Mf, out);
}

// Round 9
// 231.206 us; speedup vs baseline: 1.0554x; 1.0149x over previous
//
#include <hip/hip_runtime.h>
#include <hip/hip_bf16.h>

#define B_ 2
#define S_ 2048
#define H_ 2048
#define NH_ 16
#define NG_ 4
#define HD_ 128
#define HPG_ 4

typedef __attribute__((ext_vector_type(8))) short short8;
typedef __attribute__((ext_vector_type(4))) short short4v;
typedef __attribute__((ext_vector_type(4))) float float4v;

#define MFMA_BF16 __builtin_amdgcn_mfma_f32_16x16x32_bf16

#if __has_builtin(__builtin_amdgcn_exp2f)
#define EXP2(x) __builtin_amdgcn_exp2f(x)
#else
#define EXP2(x) exp2f(x)
#endif

// async global->LDS, 16B per lane. Per-lane lds ptr must equal wavebase + lane*16.
__device__ __forceinline__ void gload16(const void* g, void* l) {
    __builtin_amdgcn_global_load_lds(
        (const __attribute__((address_space(1))) unsigned int*)g,
        (__attribute__((address_space(3))) unsigned int*)l, 16, 0, 0);
}

__device__ __forceinline__ short bf16bits(float f) {
    union { __hip_bfloat16 h; short s; } u;
    u.h = __float2bfloat16(f);
    return u.s;
}

// ---------------- fused fp32 -> bf16 conversion + mask + bias concat ----------------
// chunk counts: hs 1048576, Wq 524288, Wk 131072, Wv 131072 -> total 1835008 = 7168*256
__global__ __launch_bounds__(256) void cvt_all(const float* __restrict__ hs,
                                               const float* __restrict__ wq,
                                               const float* __restrict__ wk,
                                               const float* __restrict__ wv,
                                               const int* __restrict__ mask,
                                               const float* __restrict__ bq,
                                               const float* __restrict__ bk,
                                               const float* __restrict__ bv,
                                               __hip_bfloat16* __restrict__ o_hs,
                                               __hip_bfloat16* __restrict__ o_wq,
                                               __hip_bfloat16* __restrict__ o_wk,
                                               __hip_bfloat16* __restrict__ o_wv,
                                               float* __restrict__ o_m,
                                               float* __restrict__ o_bc) {
    int i = blockIdx.x * 256 + threadIdx.x;
    if (blockIdx.x == 0) {
        // mask -> additive term (0 keep, -3e38 drop); exp2(-3e38) == 0
#pragma unroll
        for (int j = 0; j < 16; ++j) {
            int idx = threadIdx.x * 16 + j;
            o_m[idx] = mask[idx] ? 0.0f : -3.0e38f;
        }
    }
    if (blockIdx.x == 1) {
        // concatenated bias [3072] = bq | bk | bv
#pragma unroll
        for (int j = 0; j < 12; ++j) {
            int idx = j * 256 + threadIdx.x;
            float v = (idx < 2048) ? bq[idx] : (idx < 2560) ? bk[idx - 2048] : bv[idx - 2560];
            o_bc[idx] = v;
        }
    }
    const float* src;
    __hip_bfloat16* dst;
    int off;
    if (i < 1048576)      { src = hs; dst = o_hs; off = i; }
    else if (i < 1572864) { src = wq; dst = o_wq; off = i - 1048576; }
    else if (i < 1703936) { src = wk; dst = o_wk; off = i - 1572864; }
    else                  { src = wv; dst = o_wv; off = i - 1703936; }
    const float4* s4 = (const float4*)src;
    float4 a = s4[2 * (size_t)off];
    float4 b = s4[2 * (size_t)off + 1];
    union { short8 s; __hip_bfloat16 h[8]; } u;
    u.h[0] = __float2bfloat16(a.x); u.h[1] = __float2bfloat16(a.y);
    u.h[2] = __float2bfloat16(a.z); u.h[3] = __float2bfloat16(a.w);
    u.h[4] = __float2bfloat16(b.x); u.h[5] = __float2bfloat16(b.y);
    u.h[6] = __float2bfloat16(b.z); u.h[7] = __float2bfloat16(b.w);
    *(short8*)(dst + 8 * (size_t)off) = u.s;
}

// ---------------- fused q/k/v GEMM, 256x192 tile, 4-buffer counted-vmcnt pipeline ----------------
// (unchanged from round 2 -- verified)
__global__ __launch_bounds__(512, 2) void gemm_qkv3(const __hip_bfloat16* __restrict__ A,
                                                    const __hip_bfloat16* __restrict__ Wcat,
                                                    const float* __restrict__ biasC,
                                                    __hip_bfloat16* __restrict__ qO,
                                                    __hip_bfloat16* __restrict__ kO,
                                                    __hip_bfloat16* __restrict__ vTO) {
    extern __shared__ char lds[];  // 114688 B = 4 x 28672

    const int tid = threadIdx.x;
    const int lane = tid & 63;
    const int x = lane & 15, g = lane >> 4;
    const int wid = tid >> 6;            // 0..7
    const int wm = wid >> 2, wn = wid & 3;

    const int id0 = blockIdx.x;
    const int id = ((id0 & 7) << 5) | (id0 >> 3);
    const int bn_t = id >> 4, bm_t = id & 15;
    const int bm = bm_t * 256, bn = bn_t * 192;
    const int K = 2048;

    const int srow = tid >> 2;                         // 0..127
    const int schunk = (tid & 3) ^ ((tid >> 3) & 3);
    const __hip_bfloat16* gA0 = A + (size_t)(bm + srow) * K + schunk * 8;
    const __hip_bfloat16* gA1 = A + (size_t)(bm + 128 + srow) * K + schunk * 8;
    const __hip_bfloat16* gB0 = Wcat + (size_t)(bn + srow) * K + schunk * 8;
    const __hip_bfloat16* gB1 = Wcat + (size_t)(bn + 128 + srow) * K + schunk * 8;  // rows 128..191
    const bool doB1 = (tid < 256);

    const int xk = (x >> 1) & 3;
    int aoffA[8], boffB[3];
#pragma unroll
    for (int mb = 0; mb < 8; ++mb)
        aoffA[mb] = (wm * 128 + mb * 16 + x) * 64 + ((g ^ xk) * 16);
#pragma unroll
    for (int nb = 0; nb < 3; ++nb)
        boffB[nb] = 16384 + (wn * 48 + nb * 16 + x) * 64 + ((g ^ xk) * 16);

    float4v acc[8][3];
#pragma unroll
    for (int i = 0; i < 8; ++i)
#pragma unroll
        for (int j = 0; j < 3; ++j) acc[i][j] = (float4v)0.f;

    // prologue: stage K-tiles 0 -> buf0, 1 -> buf1
#pragma unroll
    for (int p = 0; p < 2; ++p) {
        char* stg = lds + p * 28672;
        gload16(gA0, stg + tid * 16);
        gload16(gA1, stg + 8192 + tid * 16);
        gload16(gB0, stg + 16384 + tid * 16);
        if (doB1) gload16(gB1, stg + 24576 + tid * 16);
        gA0 += 32; gA1 += 32; gB0 += 32; gB1 += 32;
    }
    if (doB1) asm volatile("s_waitcnt vmcnt(4)" ::: "memory");
    else      asm volatile("s_waitcnt vmcnt(3)" ::: "memory");
    __builtin_amdgcn_s_barrier();

#pragma unroll 4
    for (int t = 0; t < 64; ++t) {
        const char* bc = lds + (t & 3) * 28672;
        char* stg = lds + ((t + 2) & 3) * 28672;

        // ---- phase A: frags af[0..3] + all B frags; stage A of tile t+2 ----
        short8 afA[4], bfr[3];
#pragma unroll
        for (int mb = 0; mb < 4; ++mb) afA[mb] = *(const short8*)(bc + aoffA[mb]);
#pragma unroll
        for (int nb = 0; nb < 3; ++nb) bfr[nb] = *(const short8*)(bc + boffB[nb]);
        if (t < 62) {
            gload16(gA0, stg + tid * 16);
            gload16(gA1, stg + 8192 + tid * 16);
            gA0 += 32; gA1 += 32;
        }
        __builtin_amdgcn_s_barrier();
        asm volatile("s_waitcnt lgkmcnt(0)");
        __builtin_amdgcn_sched_barrier(0);
        __builtin_amdgcn_s_setprio(1);
#pragma unroll
        for (int mb = 0; mb < 4; ++mb)
#pragma unroll
            for (int nb = 0; nb < 3; ++nb)
                acc[mb][nb] = MFMA_BF16(afA[mb], bfr[nb], acc[mb][nb], 0, 0, 0);
        __builtin_amdgcn_s_setprio(0);
        __builtin_amdgcn_s_barrier();

        // ---- phase B: frags af[4..7] (B frags held in regs); stage B of tile t+2 ----
        short8 afB[4];
#pragma unroll
        for (int mb = 0; mb < 4; ++mb) afB[mb] = *(const short8*)(bc + aoffA[4 + mb]);
        if (t < 62) {
            gload16(gB0, stg + 16384 + tid * 16);
            if (doB1) gload16(gB1, stg + 24576 + tid * 16);
            gB0 += 32; gB1 += 32;
        }
        __builtin_amdgcn_s_barrier();
        asm volatile("s_waitcnt lgkmcnt(0)");
        __builtin_amdgcn_sched_barrier(0);
        __builtin_amdgcn_s_setprio(1);
#pragma unroll
        for (int mb = 0; mb < 4; ++mb)
#pragma unroll
            for (int nb = 0; nb < 3; ++nb)
                acc[4 + mb][nb] = MFMA_BF16(afB[mb], bfr[nb], acc[4 + mb][nb], 0, 0, 0);
        __builtin_amdgcn_s_setprio(0);
        if (t < 62) {
            if (doB1) asm volatile("s_waitcnt vmcnt(4)" ::: "memory");
            else      asm volatile("s_waitcnt vmcnt(3)" ::: "memory");
        } else {
            asm volatile("s_waitcnt vmcnt(0)" ::: "memory");
        }
        __builtin_amdgcn_s_barrier();
    }

    // epilogue: per-frag routing Q / K / V^T (16-col frags never straddle 2048/2560)
#pragma unroll
    for (int mb = 0; mb < 8; ++mb) {
#pragma unroll
        for (int nb = 0; nb < 3; ++nb) {
            const int n = bn + wn * 48 + nb * 16 + x;
            const float bsv = biasC[n];
            const int m0 = bm + wm * 128 + mb * 16 + g * 4;
            if (n < 2048) {
#pragma unroll
                for (int r = 0; r < 4; ++r)
                    qO[(size_t)(m0 + r) * 2048 + n] = __float2bfloat16(acc[mb][nb][r] + bsv);
            } else if (n < 2560) {
                const int nk = n - 2048;
#pragma unroll
                for (int r = 0; r < 4; ++r)
                    kO[(size_t)(m0 + r) * 512 + nk] = __float2bfloat16(acc[mb][nb][r] + bsv);
            } else {
                const int nv = n - 2560;
                const int gv = nv >> 7, d = nv & 127;
                const int bb2 = m0 >> 11, s = m0 & 2047;
                short4v pk;
#pragma unroll
                for (int r = 0; r < 4; ++r) pk[r] = bf16bits(acc[mb][nb][r] + bsv);
                *(short4v*)(vTO + ((size_t)(bb2 * NG_ + gv) * HD_ + d) * S_ + s) = pk;
            }
        }
    }
}

// ---------------- Flash attention, QBLK=256, r6 structure + Ks dbuf / alpha K-issue ----------------
// r8 post-mortem: 1-barrier fusion = null (scheduling gain eaten by spill, VGPR 128, +5MB
// scratch). Revert to r6's 2-barrier structure (80.2us, VGPR 104, no spill); single bounded
// change: double-buffer Ks and issue K(it+1)->Ks[p^1] at ALPHA (with V(it)) instead of beta.
// Both loads now covered by QK+SM (~2500cyc) before beta's vmcnt(0) drain; alpha's drain is
// free. This closes r6's only uncovered-latency window (K issued at beta had only PV cover).
// Race audit: Ks[p^1] write-issue at alpha(it) vs last reader QK(it-1) -- separated by
// alpha(it) barrier; Vs single-buffer: write post-alpha(it), prior reader PV(it-1) finished
// pre-alpha(it), drained at beta(it) before PV(it); Ps: SM writes alpha..beta, PV reads
// post-beta, next write post-alpha(it+1). LDS 83968 (1 block/CU unchanged).
// T1: XCD swizzle, 32 blocks/XCD = exactly one (b,gi) KV slice (1MB, L2-resident).
__global__ __launch_bounds__(512, 2) void attn(const __hip_bfloat16* __restrict__ q,
                                               const __hip_bfloat16* __restrict__ k,
                                               const __hip_bfloat16* __restrict__ vT,
                                               const float* __restrict__ M,
                                               float* __restrict__ out) {
    extern __shared__ char smem[];  // 83968
    char* Ks = smem;                // 2 x 16384   [t=64][d=128] chunk-xor
    char* Vs = smem + 32768;        // 16384       [d=128][t=64] chunk-xor
    char* Ps = smem + 49152;        // 34816       [q=256] rows of 136B (0-conflict)

    const int tid = threadIdx.x;
    const int lane = tid & 63;
    const int w = tid >> 6;          // 0..7
    const int wm = w >> 2, wn = w & 3;
    const int x = lane & 15, g = lane >> 4;

    // XCD-aware swizzle: 256 blocks = 8 XCDs x 32; XCD xcd = (b<<2)|gi owns its KV slice.
    const int bid0 = blockIdx.x;
    const int bid = ((bid0 & 7) << 5) | (bid0 >> 3);
    const int qt = bid & 7;
    const int hp = (bid >> 3) & 3;
    const int gi = (bid >> 5) & 3;
    const int b = bid >> 7;
    const int head = gi * HPG_ + hp;
    const int q0 = qt * 256;

    // Q B-frags in registers: B[k=d][n=q]: n = wn*64+nb*16+x, k = ks*32+g*8+j
    short8 qf[4][4];
#pragma unroll
    for (int nb = 0; nb < 4; ++nb) {
        const int qq = q0 + wn * 64 + nb * 16 + x;
        const __hip_bfloat16* qrow = q + ((size_t)(b * S_ + qq) * NH_ + head) * HD_ + g * 8;
#pragma unroll
        for (int ks = 0; ks < 4; ++ks)
            qf[nb][ks] = *(const short8*)(qrow + ks * 32);
    }

    // K staging (512 thr, 2 rounds): dest row (tid>>4)+{0,32}, chunk tid&15; src chunk ^(row&15)
    const int kchunk = (tid & 15) ^ ((tid >> 4) & 15);
    const __hip_bfloat16* kp = k + ((size_t)(b * S_ + (tid >> 4)) * NG_ + gi) * HD_ + kchunk * 8;
    // V staging (2 rounds): dest d-row (tid>>3)+{0,64}, chunk tid&7; src chunk ^(row&7)
    const int vchunk = (tid & 7) ^ ((tid >> 3) & 7);
    const __hip_bfloat16* vp = vT + ((size_t)(b * NG_ + gi) * HD_ + (tid >> 3)) * S_ + vchunk * 8;
    const float* mp = M + b * S_ + wm * 32 + g * 4;

    float4v O[4][4];
#pragma unroll
    for (int i = 0; i < 4; ++i)
#pragma unroll
        for (int j = 0; j < 4; ++j) O[i][j] = (float4v)0.f;
    float l_part[4] = {0.f, 0.f, 0.f, 0.f};

    const float SM = 0.08838834764831845f * 1.4426950408889634f;  // scale * log2(e)

    // prologue: issue K(0) -> Ks[0]
    gload16(kp, Ks + tid * 16);
    gload16(kp + 16384, Ks + tid * 16 + 8192);
    kp += 32768;  // next K tile (t advances 64 rows x 512 elem)

    for (int it = 0; it < 32; ++it) {
        __syncthreads();  // alpha: K(it) resident; PV(it-1) closed -> Vs, Ps free
        const int p = it & 1;
        const char* KsC = Ks + p * 16384;

        float4 mv0 = *(const float4*)(mp);
        float4 mv1 = *(const float4*)(mp + 16);
        mp += 64;
        // issue V(it): d-rows 0..63 and 64..127 (+64 d-rows = +131072 elem in vT)
        gload16(vp, Vs + tid * 16);
        gload16(vp + 131072, Vs + tid * 16 + 8192);
        vp += 64;
        // issue K(it+1) -> Ks[p^1]; last reader QK(it-1) finished before alpha(it)
        if (it < 31) {
            char* KsN = Ks + (p ^ 1) * 16384;
            gload16(kp, KsN + tid * 16);
            gload16(kp + 16384, KsN + tid * 16 + 8192);
            kp += 32768;
        }

        // QK^T: wave t-rows [wm*32,+32), q-cols [wn*64,+64)
        float4v sc[2][4];
#pragma unroll
        for (int i = 0; i < 2; ++i)
#pragma unroll
            for (int j = 0; j < 4; ++j) sc[i][j] = (float4v)0.f;
        __builtin_amdgcn_s_setprio(1);
#pragma unroll
        for (int ks = 0; ks < 4; ++ks) {
            short8 af0 = *(const short8*)(KsC + (wm * 32 + x) * 256 + (((ks * 4 + g) ^ x) * 16));
            short8 af1 = *(const short8*)(KsC + (wm * 32 + 16 + x) * 256 + (((ks * 4 + g) ^ x) * 16));
#pragma unroll
            for (int nb = 0; nb < 4; ++nb) {
                sc[0][nb] = MFMA_BF16(af0, qf[nb][ks], sc[0][nb], 0, 0, 0);
                sc[1][nb] = MFMA_BF16(af1, qf[nb][ks], sc[1][nb], 0, 0, 0);
            }
        }
        __builtin_amdgcn_s_setprio(0);

        // softmax numerator: p = exp2(s*SM + madd); b64 P writes (136B stride, 0-conflict)
#pragma unroll
        for (int mb = 0; mb < 2; ++mb) {
            const float4 mv = mb ? mv1 : mv0;
            const int hs = wm * 8 + mb * 4 + g;  // t-halfslot 0..15
#pragma unroll
            for (int nb = 0; nb < 4; ++nb) {
                float p0 = EXP2(fmaf(sc[mb][nb][0], SM, mv.x));
                float p1 = EXP2(fmaf(sc[mb][nb][1], SM, mv.y));
                float p2 = EXP2(fmaf(sc[mb][nb][2], SM, mv.z));
                float p3 = EXP2(fmaf(sc[mb][nb][3], SM, mv.w));
                l_part[nb] += (p0 + p1) + (p2 + p3);
                short4v pk;
                pk[0] = bf16bits(p0); pk[1] = bf16bits(p1);
                pk[2] = bf16bits(p2); pk[3] = bf16bits(p3);
                *(short4v*)(Ps + (wn * 64 + nb * 16 + x) * 136 + hs * 8) = pk;
            }
        }

        __syncthreads();  // beta: P published; V(it), K(it+1) drained (covered by QK+SM)

        // PV: O^T[d-rows wm*64+64][q-cols wn*64+64] += V^T * P
#pragma unroll
        for (int ks = 0; ks < 2; ++ks) {
            short8 vf[4], pf[4];
#pragma unroll
            for (int i4 = 0; i4 < 4; ++i4) {
                vf[i4] = *(const short8*)(Vs + (wm * 64 + i4 * 16 + x) * 128 +
                                          (((ks * 4 + g) ^ (x & 7)) * 16));
                const char* pb = Ps + (wn * 64 + i4 * 16 + x) * 136 + (8 * ks + 2 * g) * 8;
                union { short4v h[2]; short8 s8; } uu;
                uu.h[0] = *(const short4v*)pb;
                uu.h[1] = *(const short4v*)(pb + 8);
                pf[i4] = uu.s8;
            }
            __builtin_amdgcn_s_setprio(1);
#pragma unroll
            for (int mb = 0; mb < 4; ++mb)
#pragma unroll
                for (int nb = 0; nb < 4; ++nb)
                    O[mb][nb] = MFMA_BF16(vf[mb], pf[nb], O[mb][nb], 0, 0, 0);
            __builtin_amdgcn_s_setprio(0);
        }
    }

    // final l reduction: over g (shuffles), then across wm pair (LDS)
    __syncthreads();
#pragma unroll
    for (int nb = 0; nb < 4; ++nb) {
        l_part[nb] += __shfl_xor(l_part[nb], 16);
        l_part[nb] += __shfl_xor(l_part[nb], 32);
    }
    float* lws = (float*)Ps;
    if (g == 0) {
#pragma unroll
        for (int nb = 0; nb < 4; ++nb)
            lws[wm * 256 + wn * 64 + nb * 16 + x] = l_part[nb];
    }
    __syncthreads();
    float inv[4];
#pragma unroll
    for (int nb = 0; nb < 4; ++nb)
        inv[nb] = 1.0f / (l_part[nb] + lws[(wm ^ 1) * 256 + wn * 64 + nb * 16 + x]);

    // epilogue: out[b, q0+q, head*128 + d]; reg r -> consecutive d -> float4 stores
#pragma unroll
    for (int mb = 0; mb < 4; ++mb) {
#pragma unroll
        for (int nb = 0; nb < 4; ++nb) {
            const int qq = q0 + wn * 64 + nb * 16 + x;
            const int d0 = wm * 64 + mb * 16 + g * 4;
            float4v o = O[mb][nb] * inv[nb];
            *(float4v*)(out + (size_t)(b * S_ + qq) * H_ + head * HD_ + d0) = o;
        }
    }
}

extern "C" void kernel_launch(void* const* d_in, const int* in_sizes, int n_in,
                              void* d_out, int out_size, void* d_ws, size_t ws_size,
                              hipStream_t stream) {
    (void)in_sizes; (void)n_in; (void)out_size; (void)ws_size;
    const float* hs = (const float*)d_in[0];
    const int* amask = (const int*)d_in[1];
    const float* Wq = (const float*)d_in[2];
    const float* bq = (const float*)d_in[3];
    const float* Wk = (const float*)d_in[4];
    const float* bk = (const float*)d_in[5];
    const float* Wv = (const float*)d_in[6];
    const float* bv = (const float*)d_in[7];
    float* out = (float*)d_out;

    char* ws = (char*)d_ws;
    __hip_bfloat16* hsB = (__hip_bfloat16*)(ws);              // 16 MB
    __hip_bfloat16* WqB = (__hip_bfloat16*)(ws + 16777216);   // 8 MB  -- Wq|Wk|Wv contiguous = Wcat [3072][2048]
    __hip_bfloat16* WkB = (__hip_bfloat16*)(ws + 25165824);   // 2 MB
    __hip_bfloat16* WvB = (__hip_bfloat16*)(ws + 27262976);   // 2 MB
    __hip_bfloat16* qB  = (__hip_bfloat16*)(ws + 29360128);   // 16 MB  [B,S,NH,HD]
    __hip_bfloat16* kB  = (__hip_bfloat16*)(ws + 46137344);   // 4 MB   [B,S,NG,HD]
    __hip_bfloat16* vTB = (__hip_bfloat16*)(ws + 50331648);   // 4 MB   [B,NG,HD,S]
    float* Mf           = (float*)(ws + 54525952);            // 16 KB  mask additive term
    float* biasC        = (float*)(ws + 54542336);            // 12 KB  bias concat [3072]

    hipFuncSetAttribute((const void*)gemm_qkv3,
                        hipFuncAttributeMaxDynamicSharedMemorySize, 114688);
    hipFuncSetAttribute((const void*)attn,
                        hipFuncAttributeMaxDynamicSharedMemorySize, 83968);

    cvt_all<<<7168, 256, 0, stream>>>(hs, Wq, Wk, Wv, amask, bq, bk, bv,
                                      hsB, WqB, WkB, WvB, Mf, biasC);
    gemm_qkv3<<<256, 512, 114688, stream>>>(hsB, WqB, biasC, qB, kB, vTB);
    attn<<<256, 512, 83968, stream>>>(qB, kB, vTB, Mf, out);
}

// Round 10
// 226.987 us; speedup vs baseline: 1.0750x; 1.0186x over previous
//
#include <hip/hip_runtime.h>
#include <hip/hip_bf16.h>

#define B_ 2
#define S_ 2048
#define H_ 2048
#define NH_ 16
#define NG_ 4
#define HD_ 128
#define HPG_ 4

typedef __attribute__((ext_vector_type(8))) short short8;
typedef __attribute__((ext_vector_type(4))) short short4v;
typedef __attribute__((ext_vector_type(4))) float float4v;

#define MFMA_BF16 __builtin_amdgcn_mfma_f32_16x16x32_bf16

#if __has_builtin(__builtin_amdgcn_exp2f)
#define EXP2(x) __builtin_amdgcn_exp2f(x)
#else
#define EXP2(x) exp2f(x)
#endif

// async global->LDS, 16B per lane. Per-lane lds ptr must equal wavebase + lane*16.
__device__ __forceinline__ void gload16(const void* g, void* l) {
    __builtin_amdgcn_global_load_lds(
        (const __attribute__((address_space(1))) unsigned int*)g,
        (__attribute__((address_space(3))) unsigned int*)l, 16, 0, 0);
}

__device__ __forceinline__ short bf16bits(float f) {
    union { __hip_bfloat16 h; short s; } u;
    u.h = __float2bfloat16(f);
    return u.s;
}

// ---------------- fused fp32 -> bf16 conversion + mask + bias concat ----------------
// chunk counts: hs 1048576, Wq 524288, Wk 131072, Wv 131072 -> total 1835008 = 7168*256
__global__ __launch_bounds__(256) void cvt_all(const float* __restrict__ hs,
                                               const float* __restrict__ wq,
                                               const float* __restrict__ wk,
                                               const float* __restrict__ wv,
                                               const int* __restrict__ mask,
                                               const float* __restrict__ bq,
                                               const float* __restrict__ bk,
                                               const float* __restrict__ bv,
                                               __hip_bfloat16* __restrict__ o_hs,
                                               __hip_bfloat16* __restrict__ o_wq,
                                               __hip_bfloat16* __restrict__ o_wk,
                                               __hip_bfloat16* __restrict__ o_wv,
                                               float* __restrict__ o_m,
                                               float* __restrict__ o_bc) {
    int i = blockIdx.x * 256 + threadIdx.x;
    if (blockIdx.x == 0) {
        // mask -> additive term (0 keep, -3e38 drop); exp2(-3e38) == 0
#pragma unroll
        for (int j = 0; j < 16; ++j) {
            int idx = threadIdx.x * 16 + j;
            o_m[idx] = mask[idx] ? 0.0f : -3.0e38f;
        }
    }
    if (blockIdx.x == 1) {
        // concatenated bias [3072] = bq | bk | bv
#pragma unroll
        for (int j = 0; j < 12; ++j) {
            int idx = j * 256 + threadIdx.x;
            float v = (idx < 2048) ? bq[idx] : (idx < 2560) ? bk[idx - 2048] : bv[idx - 2560];
            o_bc[idx] = v;
        }
    }
    const float* src;
    __hip_bfloat16* dst;
    int off;
    if (i < 1048576)      { src = hs; dst = o_hs; off = i; }
    else if (i < 1572864) { src = wq; dst = o_wq; off = i - 1048576; }
    else if (i < 1703936) { src = wk; dst = o_wk; off = i - 1572864; }
    else                  { src = wv; dst = o_wv; off = i - 1703936; }
    const float4* s4 = (const float4*)src;
    float4 a = s4[2 * (size_t)off];
    float4 b = s4[2 * (size_t)off + 1];
    union { short8 s; __hip_bfloat16 h[8]; } u;
    u.h[0] = __float2bfloat16(a.x); u.h[1] = __float2bfloat16(a.y);
    u.h[2] = __float2bfloat16(a.z); u.h[3] = __float2bfloat16(a.w);
    u.h[4] = __float2bfloat16(b.x); u.h[5] = __float2bfloat16(b.y);
    u.h[6] = __float2bfloat16(b.z); u.h[7] = __float2bfloat16(b.w);
    *(short8*)(dst + 8 * (size_t)off) = u.s;
}

// ---------------- fused q/k/v GEMM, 256x192 tile, BK=64, minimum-2-phase ----------------
// r9 rewrite: the r2 gemm ran 4 barriers per BK=32 tile (6 MFMA/barrier/wave) -- ~5x the
// barrier frequency of the verified 2-phase reference. This is the catalog's T3-minimum
// template (m230-V0): BK=64, 2 LDS buffers, 2 barriers/tile, 48 MFMA between drains.
// Per iter: STAGE(t+1, issue-first) -> ds_read/MFMA kk=0 -> ds_read/MFMA kk=1 -> vmcnt(0)
// -> barrier. Staging: 7 uniform gloads/thread (A 4 rounds, B 3 rounds), no divergence.
// LDS layout per buffer (57344B): A [256 rows][64k] rows of 128B at +0, B [192][64] at
// +32768. Chunk-XOR: stored 16B-chunk c' at row r holds logical chunk c = c'^(r&7)
// (8 chunks/row, 128B row = all 32 banks -> XOR gives 2-way = free). Read r&7 == x&7.
// Accumulation order over k identical to r2 version (absmax preserved).
// XCD swizzle: bn-major, 2 B-panels/XCD L2-resident; grid 256 = 1 block/CU.
__global__ __launch_bounds__(512, 2) void gemm_qkv3(const __hip_bfloat16* __restrict__ A,
                                                    const __hip_bfloat16* __restrict__ Wcat,
                                                    const float* __restrict__ biasC,
                                                    __hip_bfloat16* __restrict__ qO,
                                                    __hip_bfloat16* __restrict__ kO,
                                                    __hip_bfloat16* __restrict__ vTO) {
    extern __shared__ char lds[];  // 114688 B = 2 x 57344

    const int tid = threadIdx.x;
    const int lane = tid & 63;
    const int x = lane & 15, g = lane >> 4;
    const int wid = tid >> 6;            // 0..7
    const int wm = wid >> 2, wn = wid & 3;

    const int id0 = blockIdx.x;
    const int id = ((id0 & 7) << 5) | (id0 >> 3);
    const int bn_t = id >> 4, bm_t = id & 15;
    const int bm = bm_t * 256, bn = bn_t * 192;

    // staging source: thread -> row (tid>>3) (+64 per round), stored chunk tid&7,
    // logical chunk schunk = (tid&7) ^ ((tid>>3)&7); global k-offset schunk*8.
    const int srow = tid >> 3;                         // 0..63
    const int schunk = (tid & 7) ^ (srow & 7);
    const __hip_bfloat16* gA = A + (size_t)(bm + srow) * 2048 + schunk * 8;
    const __hip_bfloat16* gB = Wcat + (size_t)(bn + srow) * 2048 + schunk * 8;

    // frag byte offsets within a buffer: row stride 128B, read chunk (kk*4+g)^(x&7)
    int aoff[8][2], boff[3][2];
#pragma unroll
    for (int mb = 0; mb < 8; ++mb)
#pragma unroll
        for (int kk = 0; kk < 2; ++kk)
            aoff[mb][kk] = (wm * 128 + mb * 16 + x) * 128 + (((kk * 4 + g) ^ (x & 7)) * 16);
#pragma unroll
    for (int nb = 0; nb < 3; ++nb)
#pragma unroll
        for (int kk = 0; kk < 2; ++kk)
            boff[nb][kk] = 32768 + (wn * 48 + nb * 16 + x) * 128 + (((kk * 4 + g) ^ (x & 7)) * 16);

    float4v acc[8][3];
#pragma unroll
    for (int i = 0; i < 8; ++i)
#pragma unroll
        for (int j = 0; j < 3; ++j) acc[i][j] = (float4v)0.f;

    // prologue: stage tile 0 -> buf 0
#pragma unroll
    for (int p = 0; p < 4; ++p)
        gload16(gA + (size_t)p * 131072, lds + p * 8192 + tid * 16);
#pragma unroll
    for (int p = 0; p < 3; ++p)
        gload16(gB + (size_t)p * 131072, lds + 32768 + p * 8192 + tid * 16);
    gA += 64; gB += 64;
    asm volatile("s_waitcnt vmcnt(0)" ::: "memory");
    __builtin_amdgcn_s_barrier();

    for (int t = 0; t < 32; ++t) {
        const char* cur = lds + (t & 1) * 57344;
        char* nxt = lds + ((t & 1) ^ 1) * 57344;

        // issue STAGE(t+1) first (T3 recipe) -- full compute phase covers the latency
        if (t < 31) {
#pragma unroll
            for (int p = 0; p < 4; ++p)
                gload16(gA + (size_t)p * 131072, nxt + p * 8192 + tid * 16);
#pragma unroll
            for (int p = 0; p < 3; ++p)
                gload16(gB + (size_t)p * 131072, nxt + 32768 + p * 8192 + tid * 16);
            gA += 64; gB += 64;
        }

        // kk = 0,1: ds_read frags then MFMA (compiler inserts fine-grained lgkmcnt)
#pragma unroll
        for (int kk = 0; kk < 2; ++kk) {
            short8 af[8], bf[3];
#pragma unroll
            for (int mb = 0; mb < 8; ++mb) af[mb] = *(const short8*)(cur + aoff[mb][kk]);
#pragma unroll
            for (int nb = 0; nb < 3; ++nb) bf[nb] = *(const short8*)(cur + boff[nb][kk]);
            __builtin_amdgcn_s_setprio(1);
#pragma unroll
            for (int mb = 0; mb < 8; ++mb)
#pragma unroll
                for (int nb = 0; nb < 3; ++nb)
                    acc[mb][nb] = MFMA_BF16(af[mb], bf[nb], acc[mb][nb], 0, 0, 0);
            __builtin_amdgcn_s_setprio(0);
        }

        // t+1 resident for next iter; cur's reads already retired (consumed by MFMA)
        asm volatile("s_waitcnt vmcnt(0)" ::: "memory");
        __builtin_amdgcn_s_barrier();
    }

    // epilogue: per-frag routing Q / K / V^T (16-col frags never straddle 2048/2560)
#pragma unroll
    for (int mb = 0; mb < 8; ++mb) {
#pragma unroll
        for (int nb = 0; nb < 3; ++nb) {
            const int n = bn + wn * 48 + nb * 16 + x;
            const float bsv = biasC[n];
            const int m0 = bm + wm * 128 + mb * 16 + g * 4;
            if (n < 2048) {
#pragma unroll
                for (int r = 0; r < 4; ++r)
                    qO[(size_t)(m0 + r) * 2048 + n] = __float2bfloat16(acc[mb][nb][r] + bsv);
            } else if (n < 2560) {
                const int nk = n - 2048;
#pragma unroll
                for (int r = 0; r < 4; ++r)
                    kO[(size_t)(m0 + r) * 512 + nk] = __float2bfloat16(acc[mb][nb][r] + bsv);
            } else {
                const int nv = n - 2560;
                const int gv = nv >> 7, d = nv & 127;
                const int bb2 = m0 >> 11, s = m0 & 2047;
                short4v pk;
#pragma unroll
                for (int r = 0; r < 4; ++r) pk[r] = bf16bits(acc[mb][nb][r] + bsv);
                *(short4v*)(vTO + ((size_t)(bb2 * NG_ + gv) * HD_ + d) * S_ + s) = pk;
            }
        }
    }
}

// ---------------- Flash attention, QBLK=256, r6 structure + Ks dbuf / alpha K-issue ----------------
// (unchanged from round 9 -- verified 81.5us; attn declared plateaued, see r8/r9 post-mortems)
__global__ __launch_bounds__(512, 2) void attn(const __hip_bfloat16* __restrict__ q,
                                               const __hip_bfloat16* __restrict__ k,
                                               const __hip_bfloat16* __restrict__ vT,
                                               const float* __restrict__ M,
                                               float* __restrict__ out) {
    extern __shared__ char smem[];  // 83968
    char* Ks = smem;                // 2 x 16384   [t=64][d=128] chunk-xor
    char* Vs = smem + 32768;        // 16384       [d=128][t=64] chunk-xor
    char* Ps = smem + 49152;        // 34816       [q=256] rows of 136B (0-conflict)

    const int tid = threadIdx.x;
    const int lane = tid & 63;
    const int w = tid >> 6;          // 0..7
    const int wm = w >> 2, wn = w & 3;
    const int x = lane & 15, g = lane >> 4;

    // XCD-aware swizzle: 256 blocks = 8 XCDs x 32; XCD xcd = (b<<2)|gi owns its KV slice.
    const int bid0 = blockIdx.x;
    const int bid = ((bid0 & 7) << 5) | (bid0 >> 3);
    const int qt = bid & 7;
    const int hp = (bid >> 3) & 3;
    const int gi = (bid >> 5) & 3;
    const int b = bid >> 7;
    const int head = gi * HPG_ + hp;
    const int q0 = qt * 256;

    // Q B-frags in registers: B[k=d][n=q]: n = wn*64+nb*16+x, k = ks*32+g*8+j
    short8 qf[4][4];
#pragma unroll
    for (int nb = 0; nb < 4; ++nb) {
        const int qq = q0 + wn * 64 + nb * 16 + x;
        const __hip_bfloat16* qrow = q + ((size_t)(b * S_ + qq) * NH_ + head) * HD_ + g * 8;
#pragma unroll
        for (int ks = 0; ks < 4; ++ks)
            qf[nb][ks] = *(const short8*)(qrow + ks * 32);
    }

    // K staging (512 thr, 2 rounds): dest row (tid>>4)+{0,32}, chunk tid&15; src chunk ^(row&15)
    const int kchunk = (tid & 15) ^ ((tid >> 4) & 15);
    const __hip_bfloat16* kp = k + ((size_t)(b * S_ + (tid >> 4)) * NG_ + gi) * HD_ + kchunk * 8;
    // V staging (2 rounds): dest d-row (tid>>3)+{0,64}, chunk tid&7; src chunk ^(row&7)
    const int vchunk = (tid & 7) ^ ((tid >> 3) & 7);
    const __hip_bfloat16* vp = vT + ((size_t)(b * NG_ + gi) * HD_ + (tid >> 3)) * S_ + vchunk * 8;
    const float* mp = M + b * S_ + wm * 32 + g * 4;

    float4v O[4][4];
#pragma unroll
    for (int i = 0; i < 4; ++i)
#pragma unroll
        for (int j = 0; j < 4; ++j) O[i][j] = (float4v)0.f;
    float l_part[4] = {0.f, 0.f, 0.f, 0.f};

    const float SM = 0.08838834764831845f * 1.4426950408889634f;  // scale * log2(e)

    // prologue: issue K(0) -> Ks[0]
    gload16(kp, Ks + tid * 16);
    gload16(kp + 16384, Ks + tid * 16 + 8192);
    kp += 32768;  // next K tile (t advances 64 rows x 512 elem)

    for (int it = 0; it < 32; ++it) {
        __syncthreads();  // alpha: K(it) resident; PV(it-1) closed -> Vs, Ps free
        const int p = it & 1;
        const char* KsC = Ks + p * 16384;

        float4 mv0 = *(const float4*)(mp);
        float4 mv1 = *(const float4*)(mp + 16);
        mp += 64;
        // issue V(it): d-rows 0..63 and 64..127 (+64 d-rows = +131072 elem in vT)
        gload16(vp, Vs + tid * 16);
        gload16(vp + 131072, Vs + tid * 16 + 8192);
        vp += 64;
        // issue K(it+1) -> Ks[p^1]; last reader QK(it-1) finished before alpha(it)
        if (it < 31) {
            char* KsN = Ks + (p ^ 1) * 16384;
            gload16(kp, KsN + tid * 16);
            gload16(kp + 16384, KsN + tid * 16 + 8192);
            kp += 32768;
        }

        // QK^T: wave t-rows [wm*32,+32), q-cols [wn*64,+64)
        float4v sc[2][4];
#pragma unroll
        for (int i = 0; i < 2; ++i)
#pragma unroll
            for (int j = 0; j < 4; ++j) sc[i][j] = (float4v)0.f;
        __builtin_amdgcn_s_setprio(1);
#pragma unroll
        for (int ks = 0; ks < 4; ++ks) {
            short8 af0 = *(const short8*)(KsC + (wm * 32 + x) * 256 + (((ks * 4 + g) ^ x) * 16));
            short8 af1 = *(const short8*)(KsC + (wm * 32 + 16 + x) * 256 + (((ks * 4 + g) ^ x) * 16));
#pragma unroll
            for (int nb = 0; nb < 4; ++nb) {
                sc[0][nb] = MFMA_BF16(af0, qf[nb][ks], sc[0][nb], 0, 0, 0);
                sc[1][nb] = MFMA_BF16(af1, qf[nb][ks], sc[1][nb], 0, 0, 0);
            }
        }
        __builtin_amdgcn_s_setprio(0);

        // softmax numerator: p = exp2(s*SM + madd); b64 P writes (136B stride, 0-conflict)
#pragma unroll
        for (int mb = 0; mb < 2; ++mb) {
            const float4 mv = mb ? mv1 : mv0;
            const int hs = wm * 8 + mb * 4 + g;  // t-halfslot 0..15
#pragma unroll
            for (int nb = 0; nb < 4; ++nb) {
                float p0 = EXP2(fmaf(sc[mb][nb][0], SM, mv.x));
                float p1 = EXP2(fmaf(sc[mb][nb][1], SM, mv.y));
                float p2 = EXP2(fmaf(sc[mb][nb][2], SM, mv.z));
                float p3 = EXP2(fmaf(sc[mb][nb][3], SM, mv.w));
                l_part[nb] += (p0 + p1) + (p2 + p3);
                short4v pk;
                pk[0] = bf16bits(p0); pk[1] = bf16bits(p1);
                pk[2] = bf16bits(p2); pk[3] = bf16bits(p3);
                *(short4v*)(Ps + (wn * 64 + nb * 16 + x) * 136 + hs * 8) = pk;
            }
        }

        __syncthreads();  // beta: P published; V(it), K(it+1) drained (covered by QK+SM)

        // PV: O^T[d-rows wm*64+64][q-cols wn*64+64] += V^T * P
#pragma unroll
        for (int ks = 0; ks < 2; ++ks) {
            short8 vf[4], pf[4];
#pragma unroll
            for (int i4 = 0; i4 < 4; ++i4) {
                vf[i4] = *(const short8*)(Vs + (wm * 64 + i4 * 16 + x) * 128 +
                                          (((ks * 4 + g) ^ (x & 7)) * 16));
                const char* pb = Ps + (wn * 64 + i4 * 16 + x) * 136 + (8 * ks + 2 * g) * 8;
                union { short4v h[2]; short8 s8; } uu;
                uu.h[0] = *(const short4v*)pb;
                uu.h[1] = *(const short4v*)(pb + 8);
                pf[i4] = uu.s8;
            }
            __builtin_amdgcn_s_setprio(1);
#pragma unroll
            for (int mb = 0; mb < 4; ++mb)
#pragma unroll
                for (int nb = 0; nb < 4; ++nb)
                    O[mb][nb] = MFMA_BF16(vf[mb], pf[nb], O[mb][nb], 0, 0, 0);
            __builtin_amdgcn_s_setprio(0);
        }
    }

    // final l reduction: over g (shuffles), then across wm pair (LDS)
    __syncthreads();
#pragma unroll
    for (int nb = 0; nb < 4; ++nb) {
        l_part[nb] += __shfl_xor(l_part[nb], 16);
        l_part[nb] += __shfl_xor(l_part[nb], 32);
    }
    float* lws = (float*)Ps;
    if (g == 0) {
#pragma unroll
        for (int nb = 0; nb < 4; ++nb)
            lws[wm * 256 + wn * 64 + nb * 16 + x] = l_part[nb];
    }
    __syncthreads();
    float inv[4];
#pragma unroll
    for (int nb = 0; nb < 4; ++nb)
        inv[nb] = 1.0f / (l_part[nb] + lws[(wm ^ 1) * 256 + wn * 64 + nb * 16 + x]);

    // epilogue: out[b, q0+q, head*128 + d]; reg r -> consecutive d -> float4 stores
#pragma unroll
    for (int mb = 0; mb < 4; ++mb) {
#pragma unroll
        for (int nb = 0; nb < 4; ++nb) {
            const int qq = q0 + wn * 64 + nb * 16 + x;
            const int d0 = wm * 64 + mb * 16 + g * 4;
            float4v o = O[mb][nb] * inv[nb];
            *(float4v*)(out + (size_t)(b * S_ + qq) * H_ + head * HD_ + d0) = o;
        }
    }
}

extern "C" void kernel_launch(void* const* d_in, const int* in_sizes, int n_in,
                              void* d_out, int out_size, void* d_ws, size_t ws_size,
                              hipStream_t stream) {
    (void)in_sizes; (void)n_in; (void)out_size; (void)ws_size;
    const float* hs = (const float*)d_in[0];
    const int* amask = (const int*)d_in[1];
    const float* Wq = (const float*)d_in[2];
    const float* bq = (const float*)d_in[3];
    const float* Wk = (const float*)d_in[4];
    const float* bk = (const float*)d_in[5];
    const float* Wv = (const float*)d_in[6];
    const float* bv = (const float*)d_in[7];
    float* out = (float*)d_out;

    char* ws = (char*)d_ws;
    __hip_bfloat16* hsB = (__hip_bfloat16*)(ws);              // 16 MB
    __hip_bfloat16* WqB = (__hip_bfloat16*)(ws + 16777216);   // 8 MB  -- Wq|Wk|Wv contiguous = Wcat [3072][2048]
    __hip_bfloat16* WkB = (__hip_bfloat16*)(ws + 25165824);   // 2 MB
    __hip_bfloat16* WvB = (__hip_bfloat16*)(ws + 27262976);   // 2 MB
    __hip_bfloat16* qB  = (__hip_bfloat16*)(ws + 29360128);   // 16 MB  [B,S,NH,HD]
    __hip_bfloat16* kB  = (__hip_bfloat16*)(ws + 46137344);   // 4 MB   [B,S,NG,HD]
    __hip_bfloat16* vTB = (__hip_bfloat16*)(ws + 50331648);   // 4 MB   [B,NG,HD,S]
    float* Mf           = (float*)(ws + 54525952);            // 16 KB  mask additive term
    float* biasC        = (float*)(ws + 54542336);            // 12 KB  bias concat [3072]

    hipFuncSetAttribute((const void*)gemm_qkv3,
                        hipFuncAttributeMaxDynamicSharedMemorySize, 114688);
    hipFuncSetAttribute((const void*)attn,
                        hipFuncAttributeMaxDynamicSharedMemorySize, 83968);

    cvt_all<<<7168, 256, 0, stream>>>(hs, Wq, Wk, Wv, amask, bq, bk, bv,
                                      hsB, WqB, WkB, WvB, Mf, biasC);
    gemm_qkv3<<<256, 512, 114688, stream>>>(hsB, WqB, biasC, qB, kB, vTB);
    attn<<<256, 512, 83968, stream>>>(qB, kB, vTB, Mf, out);
}